// Round 13
// baseline (512.239 us; speedup 1.0000x reference)
//
#include <hip/hip_runtime.h>

// SimpleGRU scan: B=2048 seqs, T=2048 steps, H=32, O=2, fp32 backbone.
// Round-13: EXACT R8 base (best: 465us, issue 352, exposure 173) + only the
// two never-isolated micro-wins (R12 bundled them with x-in-regs, which
// regressed issue +35 on its own and poisoned the test):
//  1. 4x4 dot chains (vs 2x8): +12 issue, -25 cyc dep tail on exposed path.
//  2. direct-rcp sigmoids: r gates the tanh chain; shorter r path -8 cyc
//     latency for +8 issue.
// Everything else byte-identical to R8: chunked x LDS staging (R12 proved
// register-x costs more than it saves), one-time weight pin (R10: in-loop
// pin +34 issue), f16 h LDS exchange (R11: bpermute +170 wall).

typedef _Float16 f16x2 __attribute__((ext_vector_type(2)));

__device__ __forceinline__ float fdot2(int a, int b, float c) {
    return __builtin_amdgcn_fdot2(__builtin_bit_cast(f16x2, a),
                                  __builtin_bit_cast(f16x2, b), c, false);
}

__device__ __forceinline__ int pack_pair(float a, float b) {
    f16x2 p;
    p.x = (_Float16)a;
    p.y = (_Float16)b;
    return __builtin_bit_cast(int, p);
}

__global__ __launch_bounds__(64, 1)
void gru_scan_kernel(const float* __restrict__ x,      // [B,T]
                     const float* __restrict__ w_ih,   // [96,1]
                     const float* __restrict__ w_hh,   // [96,32]
                     const float* __restrict__ b_ih,   // [96]
                     const float* __restrict__ b_hh,   // [96]
                     const float* __restrict__ head_w, // [2,32]
                     const float* __restrict__ head_b, // [2]
                     float* __restrict__ out,          // [B,2]
                     int T)
{
    const int l = (int)threadIdx.x;
    const int g = l >> 5;   // batch slot within wave
    const int j = l & 31;   // gate/hidden row
    const int b = (int)blockIdx.x * 2 + g;

    __shared__ __align__(16) _Float16 h16[2][32];   // [group][hidden] f16
    __shared__ float hf_s[2][32];                   // fp32 h for head
    __shared__ __align__(16) float x_s[2][2][32];   // [group][buf][step]

    // ---- per-lane weights: rows j (r), 32+j (z), 64+j (n), full K=32,
    // as 16 f16x2 pairs per gate = 48 int regs, one-time pin (R8 config) ----
    int wR[16], wZ[16], wN[16];
    {
        const float* pR = w_hh + (     j) * 32;
        const float* pZ = w_hh + (32 + j) * 32;
        const float* pN = w_hh + (64 + j) * 32;
#pragma unroll
        for (int q = 0; q < 16; ++q) {
            wR[q] = pack_pair(pR[2*q], pR[2*q+1]);
            wZ[q] = pack_pair(pZ[2*q], pZ[2*q+1]);
            wN[q] = pack_pair(pN[2*q], pN[2*q+1]);
        }
    }
#pragma unroll
    for (int q = 0; q < 16; ++q) {
        asm volatile("" : "+v"(wR[q]), "+v"(wZ[q]), "+v"(wN[q]));
    }

    // full-K: every lane computes complete dots -> plain per-row seeds
    const float wihr = w_ih[j];
    const float wihz = w_ih[32 + j];
    const float wihn = w_ih[64 + j];
    const float br   = b_ih[j]      + b_hh[j];
    const float bz   = b_ih[32 + j] + b_hh[32 + j];
    const float bni  = b_ih[64 + j];
    const float bnh  = b_hh[64 + j];

    const float* xrow   = x + (size_t)b * (size_t)T;
    const int    nchunk = T >> 5;   // 32-step chunks (T=2048 -> 64)

    float h = 0.0f;
    h16[g][j]    = (_Float16)0.0f;
    x_s[g][0][j] = xrow[j];
    float xnext  = (nchunk > 1) ? xrow[32 + j] : 0.0f;
    __builtin_amdgcn_wave_barrier();

    // own group's 32 h = 64 B = 4 broadcast b128 reads (group-disjoint banks)
    const int4* hq = (const int4*)(&h16[g][0]);

    for (int c = 0; c < nchunk; ++c) {
        const int buf = c & 1;
        const float* xs = &x_s[g][buf][0];
#pragma unroll 4
        for (int s = 0; s < 32; ++s) {
            const float xv = xs[s];                  // broadcast b32
            const int4 H0 = hq[0];   // h pairs 0..3
            const int4 H1 = hq[1];   // pairs 4..7
            const int4 H2 = hq[2];   // pairs 8..11
            const int4 H3 = hq[3];   // pairs 12..15

            // 4 chains of 4 dot2 per gate (16 pairs = full K=32)
            float rA = fdot2(H0.x, wR[ 0], fmaf(xv, wihr, br));
            float zA = fdot2(H0.x, wZ[ 0], fmaf(xv, wihz, bz));
            float nA = fdot2(H0.x, wN[ 0], bnh);
            rA = fdot2(H0.y, wR[ 1], rA); zA = fdot2(H0.y, wZ[ 1], zA); nA = fdot2(H0.y, wN[ 1], nA);
            rA = fdot2(H0.z, wR[ 2], rA); zA = fdot2(H0.z, wZ[ 2], zA); nA = fdot2(H0.z, wN[ 2], nA);
            rA = fdot2(H0.w, wR[ 3], rA); zA = fdot2(H0.w, wZ[ 3], zA); nA = fdot2(H0.w, wN[ 3], nA);

            float rB = fdot2(H1.x, wR[ 4], 0.0f);
            float zB = fdot2(H1.x, wZ[ 4], 0.0f);
            float nB = fdot2(H1.x, wN[ 4], 0.0f);
            rB = fdot2(H1.y, wR[ 5], rB); zB = fdot2(H1.y, wZ[ 5], zB); nB = fdot2(H1.y, wN[ 5], nB);
            rB = fdot2(H1.z, wR[ 6], rB); zB = fdot2(H1.z, wZ[ 6], zB); nB = fdot2(H1.z, wN[ 6], nB);
            rB = fdot2(H1.w, wR[ 7], rB); zB = fdot2(H1.w, wZ[ 7], zB); nB = fdot2(H1.w, wN[ 7], nB);

            float rC = fdot2(H2.x, wR[ 8], 0.0f);
            float zC = fdot2(H2.x, wZ[ 8], 0.0f);
            float nC = fdot2(H2.x, wN[ 8], 0.0f);
            rC = fdot2(H2.y, wR[ 9], rC); zC = fdot2(H2.y, wZ[ 9], zC); nC = fdot2(H2.y, wN[ 9], nC);
            rC = fdot2(H2.z, wR[10], rC); zC = fdot2(H2.z, wZ[10], zC); nC = fdot2(H2.z, wN[10], nC);
            rC = fdot2(H2.w, wR[11], rC); zC = fdot2(H2.w, wZ[11], zC); nC = fdot2(H2.w, wN[11], nC);

            float rD = fdot2(H3.x, wR[12], 0.0f);
            float zD = fdot2(H3.x, wZ[12], 0.0f);
            float nD = fdot2(H3.x, wN[12], 0.0f);
            rD = fdot2(H3.y, wR[13], rD); zD = fdot2(H3.y, wZ[13], zD); nD = fdot2(H3.y, wN[13], nD);
            rD = fdot2(H3.z, wR[14], rD); zD = fdot2(H3.z, wZ[14], zD); nD = fdot2(H3.z, wN[14], nD);
            rD = fdot2(H3.w, wR[15], rD); zD = fdot2(H3.w, wZ[15], zD); nD = fdot2(H3.w, wN[15], nD);

            const float rp = (rA + rB) + (rC + rD);
            const float zp = (zA + zB) + (zC + zD);
            const float np = (nA + nB) + (nC + nD);

            // direct-rcp sigmoids (r is on the critical path; z is late)
            const float er = __builtin_amdgcn_exp2f(rp * -1.44269504088896f);
            const float r  = __builtin_amdgcn_rcpf(1.0f + er);
            const float ez = __builtin_amdgcn_exp2f(zp * -1.44269504088896f);
            const float z  = __builtin_amdgcn_rcpf(1.0f + ez);

            // n = tanh(xn + r*np)
            const float xn = fmaf(xv, wihn, bni);
            const float u  = fmaf(r, np, xn);
            const float et = __builtin_amdgcn_exp2f(u * 2.88539008177793f);
            const float ti = __builtin_amdgcn_rcpf(1.0f + et);
            const float n  = fmaf(-2.0f, ti, 1.0f);

            h = fmaf(z, h - n, n);                   // (1-z)*n + z*h
            __builtin_amdgcn_wave_barrier();
            h16[g][j] = (_Float16)h;                 // publish for next step
            __builtin_amdgcn_wave_barrier();         // in-order DS => RAW safe
        }
        if (c + 1 < nchunk) {
            x_s[g][1 - buf][j] = xnext;              // stage next chunk
            if (c + 2 < nchunk) xnext = xrow[(c + 2) * 32 + j];
            __builtin_amdgcn_wave_barrier();
        }
    }

    // ---- head: out[b,o] = head_b[o] + sum_k h[k]*head_w[o,k] (fp32 h) ----
    hf_s[g][j] = h;
    __builtin_amdgcn_wave_barrier();
    if (l < 4) {
        const int g2 = l >> 1, o = l & 1;
        float acc = head_b[o];
        const float* hw = head_w + o * 32;
#pragma unroll
        for (int k = 0; k < 32; ++k) acc = fmaf(hf_s[g2][k], hw[k], acc);
        out[((int)blockIdx.x * 2 + g2) * 2 + o] = acc;
    }
}

extern "C" void kernel_launch(void* const* d_in, const int* in_sizes, int n_in,
                              void* d_out, int out_size, void* d_ws, size_t ws_size,
                              hipStream_t stream) {
    const float* x      = (const float*)d_in[0];
    const float* w_ih   = (const float*)d_in[1];
    const float* w_hh   = (const float*)d_in[2];
    const float* b_ih   = (const float*)d_in[3];
    const float* b_hh   = (const float*)d_in[4];
    const float* head_w = (const float*)d_in[5];
    const float* head_b = (const float*)d_in[6];
    float* out = (float*)d_out;

    const int B = out_size / 2;          // O = 2
    const int T = in_sizes[0] / B;       // x is [B,T]

    dim3 grid(B / 2), block(64);
    hipLaunchKernelGGL(gru_scan_kernel, grid, block, 0, stream,
                       x, w_ih, w_hh, b_ih, b_hh, head_w, head_b, out, T);
}